// Round 4
// baseline (246.816 us; speedup 1.0000x reference)
//
#include <hip/hip_runtime.h>

// All inputs and the output are float32 (established rounds 0-3).
// R11: R10 fixed the spill (WRITE 144MB->288KB) and mega hit 67.5us, but
// VALUBusy 26% / Occ 27% says still latency-bound: 1.5 blocks/CU and 1150-load
// serial chains. This round: (a) hoist prebias re[24][256] into the l2 kernel
// (rank-only, was recomputed 16x); (b) mega -> 768 blocks x 512 thr (2 rows/
// block, exactly 3 blocks/CU): rh = K-half split in L3/L4 with LDS partials
// (l2's proven ps2 pattern), heads parallel in G2 (acc[2]), 4-way K-split G3.
// Chains 1150 -> ~580 loads, weights read once per block (was 2x), unroll 8.

__device__ __forceinline__ float leaky(float v) { return v >= 0.f ? v : 0.2f * v; }

// ---------- D0: L1 split-K6 (slice 128): hid1p[z] = (z==0? st_b1:0) + h @ st_w1[slice z]
__global__ __launch_bounds__(256, 2) void l1_kernel(
    const float* __restrict__ h, const float* __restrict__ W,
    const float* __restrict__ bias, float* __restrict__ outp)
{
    __shared__ __align__(16) float a_lds[128][34];
    __shared__ __align__(16) float w_lds[128][34];
    const int tid = threadIdx.x;
    const int x = blockIdx.x, z = blockIdx.z;
    const int b0 = (x & 1) * 32, n0 = (x >> 1) * 32;
    const int nq = tid & 15, bq = tid >> 4;
    const int k0 = z * 128;
    float a00, a01, a10, a11;
    if (z == 0) {
        float bv0 = bias[n0 + nq * 2], bv1 = bias[n0 + nq * 2 + 1];
        a00 = bv0; a01 = bv1; a10 = bv0; a11 = bv1;
    } else { a00 = a01 = a10 = a11 = 0.f; }
    #pragma unroll
    for (int j = 0; j < 16; ++j) {
        int idx = tid + j * 256;
        int k = idx & 127, c = idx >> 7;
        a_lds[k][c] = h[(size_t)(b0 + c) * 768 + k0 + k];
        int n = idx & 31, kk = idx >> 5;
        w_lds[kk][n] = W[(size_t)(k0 + kk) * 512 + n0 + n];
    }
    __syncthreads();
    #pragma unroll 32
    for (int kk = 0; kk < 128; ++kk) {
        float2 a = *(const float2*)&a_lds[kk][bq * 2];
        float2 w = *(const float2*)&w_lds[kk][nq * 2];
        a00 += a.x * w.x; a01 += a.x * w.y;
        a10 += a.y * w.x; a11 += a.y * w.y;
    }
    float* ob = outp + (size_t)z * 32768;
    ob[(size_t)(b0 + bq * 2) * 512 + n0 + nq * 2]         = a00;
    ob[(size_t)(b0 + bq * 2) * 512 + n0 + nq * 2 + 1]     = a01;
    ob[(size_t)(b0 + bq * 2 + 1) * 512 + n0 + nq * 2]     = a10;
    ob[(size_t)(b0 + bq * 2 + 1) * 512 + n0 + nq * 2 + 1] = a11;
}

// ---------- D0b: blocks 0..31: sh = (leaky(sum6 hid1p)) @ st_w2 + st_b2 (2 rows/blk,
// K split across halves). Blocks 32..55: re[r] = rm_b1[r] + rank_emb[r] @ rm_w1[r,256:,:]
// (prebias hoisted out of mega; rank-only, K=256 split across halves).
__global__ __launch_bounds__(512, 2) void l2re_kernel(
    const float* __restrict__ hid1p, const float* __restrict__ st_w2,
    const float* __restrict__ st_b2,
    const float* __restrict__ rank_emb,
    const float* __restrict__ rm_w1, const float* __restrict__ rm_b1,
    float* __restrict__ sh, float* __restrict__ re)
{
    __shared__ __align__(16) float hid_s[2][512];
    __shared__ __align__(16) float ps2[2][2][256];
    __shared__ __align__(16) float remb_s[256];
    const int tid = threadIdx.x;
    if (blockIdx.x < 32) {
        const int b0 = blockIdx.x * 2;
        if (tid < 256) {
            int row = tid >> 7, j4 = tid & 127;
            const float4* hp = (const float4*)hid1p;
            size_t off = (size_t)(b0 + row) * 128 + j4;
            float4 v0 = hp[off],         v1 = hp[8192 + off],  v2 = hp[16384 + off];
            float4 v3 = hp[24576 + off], v4 = hp[32768 + off], v5 = hp[40960 + off];
            float4 s;
            s.x = leaky(v0.x + v1.x + v2.x + v3.x + v4.x + v5.x);
            s.y = leaky(v0.y + v1.y + v2.y + v3.y + v4.y + v5.y);
            s.z = leaky(v0.z + v1.z + v2.z + v3.z + v4.z + v5.z);
            s.w = leaky(v0.w + v1.w + v2.w + v3.w + v4.w + v5.w);
            ((float4*)&hid_s[row][0])[j4] = s;
        }
        __syncthreads();
        {
            const int col = tid & 255, kg = tid >> 8;
            const int o = kg * 256;
            float a0 = 0.f, a1 = 0.f;
            const float* wp = st_w2 + (size_t)o * 256 + col;
            #pragma unroll 4
            for (int d = 0; d < 256; d += 4) {
                float w0 = wp[(size_t)(d + 0) * 256], w1 = wp[(size_t)(d + 1) * 256];
                float w2 = wp[(size_t)(d + 2) * 256], w3 = wp[(size_t)(d + 3) * 256];
                float4 s0 = *(const float4*)&hid_s[0][o + d];
                float4 s1 = *(const float4*)&hid_s[1][o + d];
                a0 += s0.x * w0 + s0.y * w1 + s0.z * w2 + s0.w * w3;
                a1 += s1.x * w0 + s1.y * w1 + s1.z * w2 + s1.w * w3;
            }
            ps2[kg][0][col] = a0; ps2[kg][1][col] = a1;
        }
        __syncthreads();
        {
            int row = tid >> 8, c = tid & 255;
            sh[(size_t)(b0 + row) * 256 + c] = st_b2[c] + ps2[0][row][c] + ps2[1][row][c];
        }
    } else {
        const int r = blockIdx.x - 32;
        if (tid < 64)
            ((float4*)remb_s)[tid] = ((const float4*)rank_emb)[(size_t)r * 64 + tid];
        __syncthreads();
        {
            const int col = tid & 255, kh = tid >> 8;
            const int o = kh * 128;
            float acc = 0.f;
            const float* wb = rm_w1 + ((size_t)r * 512 + 256 + o) * 256 + col;
            #pragma unroll 8
            for (int d = 0; d < 128; d += 4) {
                float w0 = wb[(size_t)(d + 0) * 256], w1 = wb[(size_t)(d + 1) * 256];
                float w2 = wb[(size_t)(d + 2) * 256], w3 = wb[(size_t)(d + 3) * 256];
                float4 e = *(const float4*)&remb_s[o + d];
                acc += e.x * w0 + e.y * w1 + e.z * w2 + e.w * w3;
            }
            ps2[kh][0][col] = acc;
        }
        __syncthreads();
        if (tid < 256)
            re[(size_t)r * 256 + tid] = rm_b1[r * 256 + tid] + ps2[0][0][tid] + ps2[1][0][tid];
    }
}

// ---------- D1: mega-middle. 768 blocks x 512 thr. blk -> (r = blk%24, bt = blk/24),
// 2 batch rows per block (b0 = bt*2); col = tid&255, rh = tid>>8.
// L3/L4: rh = K-half, LDS partial ps + combine. G2: rh = head, acc[2], K=256.
// G3: 4-way K-split over 384 threads. XCD clustering: blk%8 == r%8.
__global__ __launch_bounds__(512, 4) void mega_kernel(
    const float* __restrict__ sh,
    const float* __restrict__ re,
    const float* __restrict__ rm_w1,
    const float* __restrict__ rm_w2, const float* __restrict__ rm_b2,
    const float* __restrict__ mx_w1, const float* __restrict__ mx_b1,
    const float* __restrict__ mx_w2, const float* __restrict__ mx_b2,
    const float* __restrict__ my_w1, const float* __restrict__ my_b1,
    const float* __restrict__ my_w2, const float* __restrict__ my_b2,
    const float* __restrict__ ax_w1, const float* __restrict__ ax_b1,
    const float* __restrict__ ax_w2, const float* __restrict__ ax_b2,
    const float* __restrict__ ay_w1, const float* __restrict__ ay_b1,
    const float* __restrict__ ay_w2, const float* __restrict__ ay_b2,
    float* __restrict__ Pcat)
{
    __shared__ __align__(16) float sh_s[2][256];     // 2 KB
    __shared__ __align__(16) float hdn_s[2][256];    // 2 KB
    __shared__ __align__(16) float rf_s[2][256];     // 2 KB
    __shared__ __align__(16) float hc_s[2][2][256];  // 4 KB
    __shared__ __align__(16) float ps[2][2][256];    // 4 KB (partials; reused as psf[384])
    const int tid = threadIdx.x;
    const int blk = blockIdx.x;
    const int r = blk % 24;          // blk % 8 == r % 8: rank stays on one XCD
    const int bt = blk / 24;         // 0..31
    const int b0 = bt * 2;
    const int col = tid & 255, rh = tid >> 8;

    // stage: 2 sh rows (128 float4)
    if (tid < 128)
        ((float4*)sh_s)[tid] = ((const float4*)sh)[(size_t)b0 * 64 + tid];
    __syncthreads();

    // L3 partial: K-half rh of sh @ rm_w1[r, :256, :]
    {
        float a0 = 0.f, a1 = 0.f;
        const int o = rh * 128;
        const float* wp = rm_w1 + ((size_t)r * 512 + o) * 256 + col;
        #pragma unroll 8
        for (int d = 0; d < 128; d += 4) {
            float w0 = wp[(size_t)(d + 0) * 256], w1 = wp[(size_t)(d + 1) * 256];
            float w2 = wp[(size_t)(d + 2) * 256], w3 = wp[(size_t)(d + 3) * 256];
            float4 s0 = *(const float4*)&sh_s[0][o + d];
            float4 s1 = *(const float4*)&sh_s[1][o + d];
            a0 += s0.x * w0 + s0.y * w1 + s0.z * w2 + s0.w * w3;
            a1 += s1.x * w0 + s1.y * w1 + s1.z * w2 + s1.w * w3;
        }
        ps[rh][0][col] = a0; ps[rh][1][col] = a1;
    }
    __syncthreads();
    // combine: hdn = leaky(re + ps0 + ps1)   (re already includes rm_b1)
    hdn_s[rh][col] = leaky(re[(size_t)r * 256 + col] + ps[0][rh][col] + ps[1][rh][col]);
    __syncthreads();

    // L4 partial: K-half rh of hdn @ rm_w2[r]
    {
        float a0 = 0.f, a1 = 0.f;
        const int o = rh * 128;
        const float* wp = rm_w2 + (size_t)r * 65536 + (size_t)o * 256 + col;
        #pragma unroll 8
        for (int d = 0; d < 128; d += 4) {
            float w0 = wp[(size_t)(d + 0) * 256], w1 = wp[(size_t)(d + 1) * 256];
            float w2 = wp[(size_t)(d + 2) * 256], w3 = wp[(size_t)(d + 3) * 256];
            float4 s0 = *(const float4*)&hdn_s[0][o + d];
            float4 s1 = *(const float4*)&hdn_s[1][o + d];
            a0 += s0.x * w0 + s0.y * w1 + s0.z * w2 + s0.w * w3;
            a1 += s1.x * w0 + s1.y * w1 + s1.z * w2 + s1.w * w3;
        }
        ps[rh][0][col] = a0; ps[rh][1][col] = a1;
    }
    __syncthreads();
    rf_s[rh][col] = rm_b2[r * 256 + col] + ps[0][rh][col] + ps[1][rh][col];
    __syncthreads();

    // head pointers: r<16: head0=mx(y=r), head1=my(y=16+r);
    // r>=16: rw=r-16: head0=ax(y=32+rw), head1=ay(y=40+rw)
    const float *W1, *B1, *W2_0, *B2_0, *W2_1, *B2_1; int y0, y1;
    if (r < 16) {
        y0 = r;       y1 = 16 + r;
        W2_0 = mx_w2 + (size_t)r * 6144;  B2_0 = mx_b2 + r * 24;
        W2_1 = my_w2 + (size_t)r * 6144;  B2_1 = my_b2 + r * 24;
        W1 = (rh == 0) ? mx_w1 + (size_t)r * 65536 : my_w1 + (size_t)r * 65536;
        B1 = (rh == 0) ? mx_b1 + r * 256           : my_b1 + r * 256;
    } else {
        int rw = r - 16;
        y0 = 32 + rw;  y1 = 40 + rw;
        W2_0 = ax_w2 + (size_t)rw * 6144; B2_0 = ax_b2 + rw * 24;
        W2_1 = ay_w2 + (size_t)rw * 6144; B2_1 = ay_b2 + rw * 24;
        W1 = (rh == 0) ? ax_w1 + (size_t)rw * 65536 : ay_w1 + (size_t)rw * 65536;
        B1 = (rh == 0) ? ax_b1 + rw * 256           : ay_b1 + rw * 256;
    }

    // G2 (head rh): hc[rh] = leaky(rf @ W1 + B1), both rows per thread, K=256
    {
        float bv = B1[col];
        float a0 = bv, a1 = bv;
        const float* wp = W1 + col;
        #pragma unroll 8
        for (int d = 0; d < 256; d += 4) {
            float w0 = wp[(size_t)(d + 0) * 256], w1 = wp[(size_t)(d + 1) * 256];
            float w2 = wp[(size_t)(d + 2) * 256], w3 = wp[(size_t)(d + 3) * 256];
            float4 s0 = *(const float4*)&rf_s[0][d];
            float4 s1 = *(const float4*)&rf_s[1][d];
            a0 += s0.x * w0 + s0.y * w1 + s0.z * w2 + s0.w * w3;
            a1 += s1.x * w0 + s1.y * w1 + s1.z * w2 + s1.w * w3;
        }
        hc_s[rh][0][col] = leaky(a0); hc_s[rh][1][col] = leaky(a1);
    }
    __syncthreads();

    // G3 partial: 2 heads x 2 rows x 24 cols x 4 K-quarters = 384 threads
    float* psf = &ps[0][0][0];
    if (tid < 384) {
        int o = tid >> 2, kq = tid & 3;
        int h = o / 48, rc = o % 48;
        int row = rc / 24, cj = rc - row * 24;
        const float* wp = (h ? W2_1 : W2_0) + (size_t)(kq * 64) * 24 + cj;
        const float* hp = &hc_s[h][row][kq * 64];
        float acc = 0.f;
        #pragma unroll 8
        for (int d = 0; d < 64; d += 4) {
            float w0 = wp[(d + 0) * 24], w1 = wp[(d + 1) * 24];
            float w2 = wp[(d + 2) * 24], w3 = wp[(d + 3) * 24];
            float4 s = *(const float4*)&hp[d];
            acc += s.x * w0 + s.y * w1 + s.z * w2 + s.w * w3;
        }
        psf[tid] = acc;
    }
    __syncthreads();
    if (tid < 96) {
        int h = tid / 48, rc = tid - h * 48;
        int row = rc / 24, cj = rc - row * 24;
        float v = (h ? B2_1 : B2_0)[cj]
                + psf[tid * 4] + psf[tid * 4 + 1] + psf[tid * 4 + 2] + psf[tid * 4 + 3];
        int y = h ? y1 : y0;
        Pcat[(size_t)(b0 + row) * 1152 + y * 24 + cj] = v;
    }
}

// ---------- D2: fused spline + depth (unchanged).
// Pcat rows: [Px_m 0..15, Py_m 16..31, Px_a 32..39, Py_a 40..47]
__global__ __launch_bounds__(256, 2) void depth_fused_kernel(
    const float* __restrict__ Pcat,
    const float* __restrict__ mult_w, const float* __restrict__ addx_w,
    const float* __restrict__ addy_w, const float* __restrict__ gbias,
    float* __restrict__ out)
{
    __shared__ float cp[48][25];
    __shared__ float sw[33];
    __shared__ __align__(16) float u_s[16][132];
    __shared__ __align__(16) float v_s[16][132];
    __shared__ float dx_s[128], dy_s[128];
    const int tid = threadIdx.x;
    const int b = blockIdx.z, h0 = blockIdx.y * 128, w0 = blockIdx.x * 128;
    for (int idx = tid; idx < 1152; idx += 256)
        cp[idx / 24][idx % 24] = Pcat[(size_t)b * 1152 + idx];
    if (tid == 0) {
        float e[16], m, s;
        m = -1e30f; for (int i = 0; i < 16; ++i) m = fmaxf(m, mult_w[i]);
        s = 0.f;    for (int i = 0; i < 16; ++i) { e[i] = __expf(mult_w[i] - m); s += e[i]; }
        for (int i = 0; i < 16; ++i) sw[i] = e[i] / s;
        m = -1e30f; for (int i = 0; i < 8; ++i) m = fmaxf(m, addx_w[i]);
        s = 0.f;    for (int i = 0; i < 8; ++i) { e[i] = __expf(addx_w[i] - m); s += e[i]; }
        for (int i = 0; i < 8; ++i) sw[16 + i] = e[i] / s;
        m = -1e30f; for (int i = 0; i < 8; ++i) m = fmaxf(m, addy_w[i]);
        s = 0.f;    for (int i = 0; i < 8; ++i) { e[i] = __expf(addy_w[i] - m); s += e[i]; }
        for (int i = 0; i < 8; ++i) sw[24 + i] = e[i] / s;
        sw[32] = gbias[0];
    }
    __syncthreads();
    {
        const int local = tid & 127;
        const int gpos = (tid < 128 ? w0 : h0) + local;
        const float eps = 0.001f;
        float t = eps + (float)gpos * ((1.f - 2.f * eps) / 511.f);
        float ts = t * 23.f;
        int seg = (int)ts; if (seg > 22) seg = 22;
        float tau = ts - (float)seg;
        tau = fminf(fmaxf(tau, 0.f), 0.9999f);
        float t2 = tau * tau, t3 = t2 * tau;
        float h00 = 2.f * t3 - 3.f * t2 + 1.f;
        float h10 = t3 - 2.f * t2 + tau;
        float h01 = -2.f * t3 + 3.f * t2;
        float h11 = t3 - t2;
        int sm1 = seg > 0 ? seg - 1 : 0;
        int s1 = seg + 1;
        int sp2 = s1 < 23 ? s1 + 1 : 23;
        const float msc = 0.5f / 23.f;
        auto spl = [&](int row) -> float {
            float pk = cp[row][seg], pk1 = cp[row][s1];
            float mk  = msc * (pk1 - cp[row][sm1]);
            float mk1 = msc * (cp[row][sp2] - pk);
            return h00 * pk + h10 * mk + h01 * pk1 + h11 * mk1;
        };
        if (tid < 128) {
            #pragma unroll
            for (int r = 0; r < 16; ++r) u_s[r][local] = sw[r] * spl(r);
            float dx = sw[32];
            #pragma unroll
            for (int r = 0; r < 8; ++r) dx += sw[16 + r] * spl(32 + r);
            dx_s[local] = dx;
        } else {
            #pragma unroll
            for (int r = 0; r < 16; ++r) v_s[r][local] = spl(16 + r);
            float dy = 0.f;
            #pragma unroll
            for (int r = 0; r < 8; ++r) dy += sw[24 + r] * spl(40 + r);
            dy_s[local] = dy;
        }
    }
    __syncthreads();
    const int tw = tid & 15, th = tid >> 4;
    float acc[8][8];
    #pragma unroll
    for (int i = 0; i < 8; ++i)
        #pragma unroll
        for (int j = 0; j < 8; ++j) acc[i][j] = 0.f;
    #pragma unroll
    for (int r = 0; r < 16; ++r) {
        float4 va0 = *(const float4*)&v_s[r][th * 8];
        float4 va1 = *(const float4*)&v_s[r][th * 8 + 4];
        float4 ub0 = *(const float4*)&u_s[r][tw * 8];
        float4 ub1 = *(const float4*)&u_s[r][tw * 8 + 4];
        float va[8] = {va0.x, va0.y, va0.z, va0.w, va1.x, va1.y, va1.z, va1.w};
        float ub[8] = {ub0.x, ub0.y, ub0.z, ub0.w, ub1.x, ub1.y, ub1.z, ub1.w};
        #pragma unroll
        for (int i = 0; i < 8; ++i)
            #pragma unroll
            for (int j = 0; j < 8; ++j)
                acc[i][j] += va[i] * ub[j];
    }
    #pragma unroll
    for (int i = 0; i < 8; ++i) {
        float dyh = dy_s[th * 8 + i];
        float* op = out + (size_t)b * 262144 + (size_t)(h0 + th * 8 + i) * 512 + w0 + tw * 8;
        float4 o0, o1;
        o0.x = acc[i][0] + dx_s[tw * 8 + 0] + dyh;
        o0.y = acc[i][1] + dx_s[tw * 8 + 1] + dyh;
        o0.z = acc[i][2] + dx_s[tw * 8 + 2] + dyh;
        o0.w = acc[i][3] + dx_s[tw * 8 + 3] + dyh;
        o1.x = acc[i][4] + dx_s[tw * 8 + 4] + dyh;
        o1.y = acc[i][5] + dx_s[tw * 8 + 5] + dyh;
        o1.z = acc[i][6] + dx_s[tw * 8 + 6] + dyh;
        o1.w = acc[i][7] + dx_s[tw * 8 + 7] + dyh;
        *(float4*)op = o0;
        *(float4*)(op + 4) = o1;
    }
}

// ---------- host ----------
extern "C" void kernel_launch(void* const* d_in, const int* in_sizes, int n_in,
                              void* d_out, int out_size, void* d_ws, size_t ws_size,
                              hipStream_t stream) {
    const float* in_h     = (const float*)d_in[0];
    const float* rank_emb = (const float*)d_in[1];
    const float* st_w1    = (const float*)d_in[2];
    const float* st_b1    = (const float*)d_in[3];
    const float* st_w2    = (const float*)d_in[4];
    const float* st_b2    = (const float*)d_in[5];
    const float* rm_w1    = (const float*)d_in[6];
    const float* rm_b1    = (const float*)d_in[7];
    const float* rm_w2    = (const float*)d_in[8];
    const float* rm_b2    = (const float*)d_in[9];
    const float* mx_w1    = (const float*)d_in[10];
    const float* mx_b1    = (const float*)d_in[11];
    const float* mx_w2    = (const float*)d_in[12];
    const float* mx_b2    = (const float*)d_in[13];
    const float* my_w1    = (const float*)d_in[14];
    const float* my_b1    = (const float*)d_in[15];
    const float* my_w2    = (const float*)d_in[16];
    const float* my_b2    = (const float*)d_in[17];
    const float* ax_w1    = (const float*)d_in[18];
    const float* ax_b1    = (const float*)d_in[19];
    const float* ax_w2    = (const float*)d_in[20];
    const float* ax_b2    = (const float*)d_in[21];
    const float* ay_w1    = (const float*)d_in[22];
    const float* ay_b1    = (const float*)d_in[23];
    const float* ay_w2    = (const float*)d_in[24];
    const float* ay_b2    = (const float*)d_in[25];
    const float* mult_w   = (const float*)d_in[26];
    const float* addx_w   = (const float*)d_in[27];
    const float* addy_w   = (const float*)d_in[28];
    const float* gbias    = (const float*)d_in[29];
    (void)in_sizes; (void)n_in; (void)out_size; (void)ws_size;

    float* ws = (float*)d_ws;
    float* hid1p = ws;               // 6 x (64x512) = 196608 floats
    float* Pcat  = ws + 196608;      // 64x48x24     = 73728 floats
    float* shbuf = ws + 270336;      // 64x256       = 16384 floats
    float* rebuf = ws + 286720;      // 24x256       = 6144 floats

    // D0: L1 split-K6 -> hid1p[6]
    l1_kernel<<<dim3(32, 1, 6), 256, 0, stream>>>(in_h, st_w1, st_b1, hid1p);

    // D0b: shared layer 2 (once) + prebias re[24][256] (once)
    l2re_kernel<<<56, 512, 0, stream>>>(hid1p, st_w2, st_b2,
                                        rank_emb, rm_w1, rm_b1, shbuf, rebuf);

    // D1: mega-middle -> Pcat (768 blocks, XCD-clustered by rank)
    mega_kernel<<<768, 512, 0, stream>>>(
        shbuf, rebuf,
        rm_w1, rm_w2, rm_b2,
        mx_w1, mx_b1, mx_w2, mx_b2,
        my_w1, my_b1, my_w2, my_b2,
        ax_w1, ax_b1, ax_w2, ax_b2,
        ay_w1, ay_b1, ay_w2, ay_b2,
        Pcat);

    // D2: fused spline + depth
    depth_fused_kernel<<<dim3(4, 4, 64), 256, 0, stream>>>(
        Pcat, mult_w, addx_w, addy_w, gbias, (float*)d_out);
}

// Round 5
// 228.724 us; speedup vs baseline: 1.0791x; 1.0791x over previous
//
#include <hip/hip_runtime.h>

// All inputs and the output are float32 (established rounds 0-3).
// R12: R11 regressed (74us): unroll-8 re-spilled (WRITE 17MB, VGPR 64) and
// 2-rows/block halved arithmetic intensity (FETCH 16->25MB, L2 thrash).
// This round: mega = R10's proven no-spill envelope (384 blk x 512 thr, 4 rows,
// unroll 4, VGPR ~44) + R11's good ideas done right: L3/L4 K-half split over rh
// (weight reads/block halved, chains 256->128), G2 head-split acc[4], G3 2-way
// K-split, prebias hoisted + re staged in LDS. l2re regridded 56 -> 176 blocks
// (sh: 64 rows x 2 col-halves x K/4; re: 24 ranks x 2 col-halves x K/4).

__device__ __forceinline__ float leaky(float v) { return v >= 0.f ? v : 0.2f * v; }

// ---------- D0: L1 split-K6 (slice 128): hid1p[z] = (z==0? st_b1:0) + h @ st_w1[slice z]
__global__ __launch_bounds__(256, 2) void l1_kernel(
    const float* __restrict__ h, const float* __restrict__ W,
    const float* __restrict__ bias, float* __restrict__ outp)
{
    __shared__ __align__(16) float a_lds[128][34];
    __shared__ __align__(16) float w_lds[128][34];
    const int tid = threadIdx.x;
    const int x = blockIdx.x, z = blockIdx.z;
    const int b0 = (x & 1) * 32, n0 = (x >> 1) * 32;
    const int nq = tid & 15, bq = tid >> 4;
    const int k0 = z * 128;
    float a00, a01, a10, a11;
    if (z == 0) {
        float bv0 = bias[n0 + nq * 2], bv1 = bias[n0 + nq * 2 + 1];
        a00 = bv0; a01 = bv1; a10 = bv0; a11 = bv1;
    } else { a00 = a01 = a10 = a11 = 0.f; }
    #pragma unroll
    for (int j = 0; j < 16; ++j) {
        int idx = tid + j * 256;
        int k = idx & 127, c = idx >> 7;
        a_lds[k][c] = h[(size_t)(b0 + c) * 768 + k0 + k];
        int n = idx & 31, kk = idx >> 5;
        w_lds[kk][n] = W[(size_t)(k0 + kk) * 512 + n0 + n];
    }
    __syncthreads();
    #pragma unroll 32
    for (int kk = 0; kk < 128; ++kk) {
        float2 a = *(const float2*)&a_lds[kk][bq * 2];
        float2 w = *(const float2*)&w_lds[kk][nq * 2];
        a00 += a.x * w.x; a01 += a.x * w.y;
        a10 += a.y * w.x; a11 += a.y * w.y;
    }
    float* ob = outp + (size_t)z * 32768;
    ob[(size_t)(b0 + bq * 2) * 512 + n0 + nq * 2]         = a00;
    ob[(size_t)(b0 + bq * 2) * 512 + n0 + nq * 2 + 1]     = a01;
    ob[(size_t)(b0 + bq * 2 + 1) * 512 + n0 + nq * 2]     = a10;
    ob[(size_t)(b0 + bq * 2 + 1) * 512 + n0 + nq * 2 + 1] = a11;
}

// ---------- D0b: 176 blocks x 512 thr.
// blocks 0..127:  sh[row][ch*128..+128] = (leaky(sum6 hid1p))[row] @ st_w2 + st_b2
//                 (row = blk>>1, ch = blk&1; threads = 128 cols x 4 K-quarters)
// blocks 128..175: re[r][ch*128..+128] = rm_b1[r] + rank_emb[r] @ rm_w1[r,256:,:]
//                 (r = (blk-128)>>1, ch = (blk-128)&1; 128 cols x 4 K-quarters)
__global__ __launch_bounds__(512, 2) void l2re_kernel(
    const float* __restrict__ hid1p, const float* __restrict__ st_w2,
    const float* __restrict__ st_b2,
    const float* __restrict__ rank_emb,
    const float* __restrict__ rm_w1, const float* __restrict__ rm_b1,
    float* __restrict__ sh, float* __restrict__ re)
{
    __shared__ __align__(16) float hid_s[512];
    __shared__ __align__(16) float ps[4][128];
    const int tid = threadIdx.x;
    const int blk = blockIdx.x;
    if (blk < 128) {
        const int row = blk >> 1, ch = blk & 1;
        if (tid < 128) {
            const float4* hp = (const float4*)hid1p;
            size_t off = (size_t)row * 128 + tid;
            float4 v0 = hp[off],         v1 = hp[8192 + off],  v2 = hp[16384 + off];
            float4 v3 = hp[24576 + off], v4 = hp[32768 + off], v5 = hp[40960 + off];
            float4 s;
            s.x = leaky(v0.x + v1.x + v2.x + v3.x + v4.x + v5.x);
            s.y = leaky(v0.y + v1.y + v2.y + v3.y + v4.y + v5.y);
            s.z = leaky(v0.z + v1.z + v2.z + v3.z + v4.z + v5.z);
            s.w = leaky(v0.w + v1.w + v2.w + v3.w + v4.w + v5.w);
            ((float4*)hid_s)[tid] = s;
        }
        __syncthreads();
        {
            const int c = tid & 127, kq = tid >> 7;   // 0..3
            const int o = kq * 128;
            const int col = ch * 128 + c;
            float acc = 0.f;
            const float* wp = st_w2 + (size_t)o * 256 + col;
            #pragma unroll 4
            for (int d = 0; d < 128; d += 4) {
                float w0 = wp[(size_t)(d + 0) * 256], w1 = wp[(size_t)(d + 1) * 256];
                float w2 = wp[(size_t)(d + 2) * 256], w3 = wp[(size_t)(d + 3) * 256];
                float4 s = *(const float4*)&hid_s[o + d];
                acc += s.x * w0 + s.y * w1 + s.z * w2 + s.w * w3;
            }
            ps[kq][c] = acc;
        }
        __syncthreads();
        if (tid < 128) {
            int col = ch * 128 + tid;
            sh[(size_t)row * 256 + col] = st_b2[col]
                + ps[0][tid] + ps[1][tid] + ps[2][tid] + ps[3][tid];
        }
    } else {
        const int q = blk - 128;
        const int r = q >> 1, ch = q & 1;
        if (tid < 64)
            ((float4*)hid_s)[tid] = ((const float4*)rank_emb)[(size_t)r * 64 + tid];
        __syncthreads();
        {
            const int c = tid & 127, kq = tid >> 7;   // 0..3
            const int o = kq * 64;
            const int col = ch * 128 + c;
            float acc = 0.f;
            const float* wb = rm_w1 + ((size_t)r * 512 + 256 + o) * 256 + col;
            #pragma unroll 4
            for (int d = 0; d < 64; d += 4) {
                float w0 = wb[(size_t)(d + 0) * 256], w1 = wb[(size_t)(d + 1) * 256];
                float w2 = wb[(size_t)(d + 2) * 256], w3 = wb[(size_t)(d + 3) * 256];
                float4 e = *(const float4*)&hid_s[o + d];
                acc += e.x * w0 + e.y * w1 + e.z * w2 + e.w * w3;
            }
            ps[kq][c] = acc;
        }
        __syncthreads();
        if (tid < 128) {
            int col = ch * 128 + tid;
            re[(size_t)r * 256 + col] = rm_b1[r * 256 + col]
                + ps[0][tid] + ps[1][tid] + ps[2][tid] + ps[3][tid];
        }
    }
}

// ---------- D1: mega-middle. 384 blocks x 512 thr. blk -> (r = blk%24, bt = blk/24),
// 4 batch rows per block (b0 = bt*4); col = tid&255, rh = tid>>8.
// L3/L4: rh = K-half, acc[4] rows, LDS partials + combine (weights read once/blk).
// G2: rh = head, acc[4], full K=256. G3: 2-way K-split over 384 threads.
// All inner loops unroll 4 (16 loads in flight -- R10's proven no-spill depth).
__global__ __launch_bounds__(512, 4) void mega_kernel(
    const float* __restrict__ sh,
    const float* __restrict__ re,
    const float* __restrict__ rm_w1,
    const float* __restrict__ rm_w2, const float* __restrict__ rm_b2,
    const float* __restrict__ mx_w1, const float* __restrict__ mx_b1,
    const float* __restrict__ mx_w2, const float* __restrict__ mx_b2,
    const float* __restrict__ my_w1, const float* __restrict__ my_b1,
    const float* __restrict__ my_w2, const float* __restrict__ my_b2,
    const float* __restrict__ ax_w1, const float* __restrict__ ax_b1,
    const float* __restrict__ ax_w2, const float* __restrict__ ax_b2,
    const float* __restrict__ ay_w1, const float* __restrict__ ay_b1,
    const float* __restrict__ ay_w2, const float* __restrict__ ay_b2,
    float* __restrict__ Pcat)
{
    __shared__ __align__(16) float sh_s[4][256];     // 4 KB
    __shared__ __align__(16) float hdn_s[4][256];    // 4 KB
    __shared__ __align__(16) float rf_s[4][256];     // 4 KB
    __shared__ __align__(16) float hc_s[2][4][256];  // 8 KB
    __shared__ __align__(16) float ps[2][4][256];    // 8 KB (partials; reused as psf)
    __shared__ __align__(16) float re_s[256];        // 1 KB  (total ~29 KB)
    const int tid = threadIdx.x;
    const int blk = blockIdx.x;
    const int r = blk % 24;          // blk % 8 == r % 8: rank stays on one XCD
    const int bt = blk / 24;         // 0..15
    const int b0 = bt * 4;
    const int col = tid & 255, rh = tid >> 8;

    // stage: 4 sh rows (256 float4) + re row (64 float4)
    if (tid < 256) {
        ((float4*)sh_s)[tid] = ((const float4*)sh)[(size_t)b0 * 64 + tid];
    } else if (tid < 320) {
        int j4 = tid - 256;
        ((float4*)re_s)[j4] = ((const float4*)re)[(size_t)r * 64 + j4];
    }
    __syncthreads();

    // L3 partial: K-half rh of sh @ rm_w1[r, :256, :], 4 rows
    {
        float a0 = 0.f, a1 = 0.f, a2 = 0.f, a3 = 0.f;
        const int o = rh * 128;
        const float* wp = rm_w1 + ((size_t)r * 512 + o) * 256 + col;
        #pragma unroll 4
        for (int d = 0; d < 128; d += 4) {
            float w0 = wp[(size_t)(d + 0) * 256], w1 = wp[(size_t)(d + 1) * 256];
            float w2 = wp[(size_t)(d + 2) * 256], w3 = wp[(size_t)(d + 3) * 256];
            float4 s0 = *(const float4*)&sh_s[0][o + d];
            float4 s1 = *(const float4*)&sh_s[1][o + d];
            float4 s2 = *(const float4*)&sh_s[2][o + d];
            float4 s3 = *(const float4*)&sh_s[3][o + d];
            a0 += s0.x * w0 + s0.y * w1 + s0.z * w2 + s0.w * w3;
            a1 += s1.x * w0 + s1.y * w1 + s1.z * w2 + s1.w * w3;
            a2 += s2.x * w0 + s2.y * w1 + s2.z * w2 + s2.w * w3;
            a3 += s3.x * w0 + s3.y * w1 + s3.z * w2 + s3.w * w3;
        }
        ps[rh][0][col] = a0; ps[rh][1][col] = a1;
        ps[rh][2][col] = a2; ps[rh][3][col] = a3;
    }
    __syncthreads();
    // combine: hdn = leaky(re + ps0 + ps1)   (re includes rm_b1 + prebias)
    #pragma unroll
    for (int t = 0; t < 2; ++t) {
        int o2 = tid + t * 512;
        int i = o2 >> 8, c = o2 & 255;
        hdn_s[i][c] = leaky(re_s[c] + ps[0][i][c] + ps[1][i][c]);
    }
    __syncthreads();

    // L4 partial: K-half rh of hdn @ rm_w2[r], 4 rows
    {
        float a0 = 0.f, a1 = 0.f, a2 = 0.f, a3 = 0.f;
        const int o = rh * 128;
        const float* wp = rm_w2 + (size_t)r * 65536 + (size_t)o * 256 + col;
        #pragma unroll 4
        for (int d = 0; d < 128; d += 4) {
            float w0 = wp[(size_t)(d + 0) * 256], w1 = wp[(size_t)(d + 1) * 256];
            float w2 = wp[(size_t)(d + 2) * 256], w3 = wp[(size_t)(d + 3) * 256];
            float4 s0 = *(const float4*)&hdn_s[0][o + d];
            float4 s1 = *(const float4*)&hdn_s[1][o + d];
            float4 s2 = *(const float4*)&hdn_s[2][o + d];
            float4 s3 = *(const float4*)&hdn_s[3][o + d];
            a0 += s0.x * w0 + s0.y * w1 + s0.z * w2 + s0.w * w3;
            a1 += s1.x * w0 + s1.y * w1 + s1.z * w2 + s1.w * w3;
            a2 += s2.x * w0 + s2.y * w1 + s2.z * w2 + s2.w * w3;
            a3 += s3.x * w0 + s3.y * w1 + s3.z * w2 + s3.w * w3;
        }
        ps[rh][0][col] = a0; ps[rh][1][col] = a1;
        ps[rh][2][col] = a2; ps[rh][3][col] = a3;
    }
    __syncthreads();
    {
        float bv;
        #pragma unroll
        for (int t = 0; t < 2; ++t) {
            int o2 = tid + t * 512;
            int i = o2 >> 8, c = o2 & 255;
            bv = rm_b2[r * 256 + c];
            rf_s[i][c] = bv + ps[0][i][c] + ps[1][i][c];
        }
    }
    __syncthreads();

    // head pointers: r<16: head0=mx(y=r), head1=my(y=16+r);
    // r>=16: rw=r-16: head0=ax(y=32+rw), head1=ay(y=40+rw)
    const float *W1, *B1, *W2_0, *B2_0, *W2_1, *B2_1; int y0, y1;
    if (r < 16) {
        y0 = r;       y1 = 16 + r;
        W2_0 = mx_w2 + (size_t)r * 6144;  B2_0 = mx_b2 + r * 24;
        W2_1 = my_w2 + (size_t)r * 6144;  B2_1 = my_b2 + r * 24;
        W1 = (rh == 0) ? mx_w1 + (size_t)r * 65536 : my_w1 + (size_t)r * 65536;
        B1 = (rh == 0) ? mx_b1 + r * 256           : my_b1 + r * 256;
    } else {
        int rw = r - 16;
        y0 = 32 + rw;  y1 = 40 + rw;
        W2_0 = ax_w2 + (size_t)rw * 6144; B2_0 = ax_b2 + rw * 24;
        W2_1 = ay_w2 + (size_t)rw * 6144; B2_1 = ay_b2 + rw * 24;
        W1 = (rh == 0) ? ax_w1 + (size_t)rw * 65536 : ay_w1 + (size_t)rw * 65536;
        B1 = (rh == 0) ? ax_b1 + rw * 256           : ay_b1 + rw * 256;
    }

    // G2 (head rh): hc[rh] = leaky(rf @ W1 + B1), all 4 rows, K=256
    {
        float bv = B1[col];
        float acc0 = bv, acc1 = bv, acc2 = bv, acc3 = bv;
        const float* wp = W1 + col;
        #pragma unroll 4
        for (int d = 0; d < 256; d += 4) {
            float w0 = wp[(size_t)(d + 0) * 256], w1 = wp[(size_t)(d + 1) * 256];
            float w2 = wp[(size_t)(d + 2) * 256], w3 = wp[(size_t)(d + 3) * 256];
            float4 s0 = *(const float4*)&rf_s[0][d];
            float4 s1 = *(const float4*)&rf_s[1][d];
            float4 s2 = *(const float4*)&rf_s[2][d];
            float4 s3 = *(const float4*)&rf_s[3][d];
            acc0 += s0.x * w0 + s0.y * w1 + s0.z * w2 + s0.w * w3;
            acc1 += s1.x * w0 + s1.y * w1 + s1.z * w2 + s1.w * w3;
            acc2 += s2.x * w0 + s2.y * w1 + s2.z * w2 + s2.w * w3;
            acc3 += s3.x * w0 + s3.y * w1 + s3.z * w2 + s3.w * w3;
        }
        hc_s[rh][0][col] = leaky(acc0); hc_s[rh][1][col] = leaky(acc1);
        hc_s[rh][2][col] = leaky(acc2); hc_s[rh][3][col] = leaky(acc3);
    }
    __syncthreads();

    // G3 partial: 2 heads x 4 rows x 24 cols x 2 K-halves = 384 threads
    float* psf = &ps[0][0][0];
    if (tid < 384) {
        int o = tid >> 1, kq = tid & 1;
        int h = o / 96, rc = o % 96;
        int row = rc / 24, cj = rc - row * 24;
        const float* wp = (h ? W2_1 : W2_0) + (size_t)(kq * 128) * 24 + cj;
        const float* hp = &hc_s[h][row][kq * 128];
        float acc = 0.f;
        #pragma unroll 4
        for (int d = 0; d < 128; d += 4) {
            float w0 = wp[(d + 0) * 24], w1 = wp[(d + 1) * 24];
            float w2 = wp[(d + 2) * 24], w3 = wp[(d + 3) * 24];
            float4 s = *(const float4*)&hp[d];
            acc += s.x * w0 + s.y * w1 + s.z * w2 + s.w * w3;
        }
        psf[tid] = acc;
    }
    __syncthreads();
    if (tid < 192) {
        int h = tid / 96, rc = tid - h * 96;
        int row = rc / 24, cj = rc - row * 24;
        float v = (h ? B2_1 : B2_0)[cj] + psf[tid * 2] + psf[tid * 2 + 1];
        int y = h ? y1 : y0;
        Pcat[(size_t)(b0 + row) * 1152 + y * 24 + cj] = v;
    }
}

// ---------- D2: fused spline + depth (unchanged).
// Pcat rows: [Px_m 0..15, Py_m 16..31, Px_a 32..39, Py_a 40..47]
__global__ __launch_bounds__(256, 2) void depth_fused_kernel(
    const float* __restrict__ Pcat,
    const float* __restrict__ mult_w, const float* __restrict__ addx_w,
    const float* __restrict__ addy_w, const float* __restrict__ gbias,
    float* __restrict__ out)
{
    __shared__ float cp[48][25];
    __shared__ float sw[33];
    __shared__ __align__(16) float u_s[16][132];
    __shared__ __align__(16) float v_s[16][132];
    __shared__ float dx_s[128], dy_s[128];
    const int tid = threadIdx.x;
    const int b = blockIdx.z, h0 = blockIdx.y * 128, w0 = blockIdx.x * 128;
    for (int idx = tid; idx < 1152; idx += 256)
        cp[idx / 24][idx % 24] = Pcat[(size_t)b * 1152 + idx];
    if (tid == 0) {
        float e[16], m, s;
        m = -1e30f; for (int i = 0; i < 16; ++i) m = fmaxf(m, mult_w[i]);
        s = 0.f;    for (int i = 0; i < 16; ++i) { e[i] = __expf(mult_w[i] - m); s += e[i]; }
        for (int i = 0; i < 16; ++i) sw[i] = e[i] / s;
        m = -1e30f; for (int i = 0; i < 8; ++i) m = fmaxf(m, addx_w[i]);
        s = 0.f;    for (int i = 0; i < 8; ++i) { e[i] = __expf(addx_w[i] - m); s += e[i]; }
        for (int i = 0; i < 8; ++i) sw[16 + i] = e[i] / s;
        m = -1e30f; for (int i = 0; i < 8; ++i) m = fmaxf(m, addy_w[i]);
        s = 0.f;    for (int i = 0; i < 8; ++i) { e[i] = __expf(addy_w[i] - m); s += e[i]; }
        for (int i = 0; i < 8; ++i) sw[24 + i] = e[i] / s;
        sw[32] = gbias[0];
    }
    __syncthreads();
    {
        const int local = tid & 127;
        const int gpos = (tid < 128 ? w0 : h0) + local;
        const float eps = 0.001f;
        float t = eps + (float)gpos * ((1.f - 2.f * eps) / 511.f);
        float ts = t * 23.f;
        int seg = (int)ts; if (seg > 22) seg = 22;
        float tau = ts - (float)seg;
        tau = fminf(fmaxf(tau, 0.f), 0.9999f);
        float t2 = tau * tau, t3 = t2 * tau;
        float h00 = 2.f * t3 - 3.f * t2 + 1.f;
        float h10 = t3 - 2.f * t2 + tau;
        float h01 = -2.f * t3 + 3.f * t2;
        float h11 = t3 - t2;
        int sm1 = seg > 0 ? seg - 1 : 0;
        int s1 = seg + 1;
        int sp2 = s1 < 23 ? s1 + 1 : 23;
        const float msc = 0.5f / 23.f;
        auto spl = [&](int row) -> float {
            float pk = cp[row][seg], pk1 = cp[row][s1];
            float mk  = msc * (pk1 - cp[row][sm1]);
            float mk1 = msc * (cp[row][sp2] - pk);
            return h00 * pk + h10 * mk + h01 * pk1 + h11 * mk1;
        };
        if (tid < 128) {
            #pragma unroll
            for (int r = 0; r < 16; ++r) u_s[r][local] = sw[r] * spl(r);
            float dx = sw[32];
            #pragma unroll
            for (int r = 0; r < 8; ++r) dx += sw[16 + r] * spl(32 + r);
            dx_s[local] = dx;
        } else {
            #pragma unroll
            for (int r = 0; r < 16; ++r) v_s[r][local] = spl(16 + r);
            float dy = 0.f;
            #pragma unroll
            for (int r = 0; r < 8; ++r) dy += sw[24 + r] * spl(40 + r);
            dy_s[local] = dy;
        }
    }
    __syncthreads();
    const int tw = tid & 15, th = tid >> 4;
    float acc[8][8];
    #pragma unroll
    for (int i = 0; i < 8; ++i)
        #pragma unroll
        for (int j = 0; j < 8; ++j) acc[i][j] = 0.f;
    #pragma unroll
    for (int r = 0; r < 16; ++r) {
        float4 va0 = *(const float4*)&v_s[r][th * 8];
        float4 va1 = *(const float4*)&v_s[r][th * 8 + 4];
        float4 ub0 = *(const float4*)&u_s[r][tw * 8];
        float4 ub1 = *(const float4*)&u_s[r][tw * 8 + 4];
        float va[8] = {va0.x, va0.y, va0.z, va0.w, va1.x, va1.y, va1.z, va1.w};
        float ub[8] = {ub0.x, ub0.y, ub0.z, ub0.w, ub1.x, ub1.y, ub1.z, ub1.w};
        #pragma unroll
        for (int i = 0; i < 8; ++i)
            #pragma unroll
            for (int j = 0; j < 8; ++j)
                acc[i][j] += va[i] * ub[j];
    }
    #pragma unroll
    for (int i = 0; i < 8; ++i) {
        float dyh = dy_s[th * 8 + i];
        float* op = out + (size_t)b * 262144 + (size_t)(h0 + th * 8 + i) * 512 + w0 + tw * 8;
        float4 o0, o1;
        o0.x = acc[i][0] + dx_s[tw * 8 + 0] + dyh;
        o0.y = acc[i][1] + dx_s[tw * 8 + 1] + dyh;
        o0.z = acc[i][2] + dx_s[tw * 8 + 2] + dyh;
        o0.w = acc[i][3] + dx_s[tw * 8 + 3] + dyh;
        o1.x = acc[i][4] + dx_s[tw * 8 + 4] + dyh;
        o1.y = acc[i][5] + dx_s[tw * 8 + 5] + dyh;
        o1.z = acc[i][6] + dx_s[tw * 8 + 6] + dyh;
        o1.w = acc[i][7] + dx_s[tw * 8 + 7] + dyh;
        *(float4*)op = o0;
        *(float4*)(op + 4) = o1;
    }
}

// ---------- host ----------
extern "C" void kernel_launch(void* const* d_in, const int* in_sizes, int n_in,
                              void* d_out, int out_size, void* d_ws, size_t ws_size,
                              hipStream_t stream) {
    const float* in_h     = (const float*)d_in[0];
    const float* rank_emb = (const float*)d_in[1];
    const float* st_w1    = (const float*)d_in[2];
    const float* st_b1    = (const float*)d_in[3];
    const float* st_w2    = (const float*)d_in[4];
    const float* st_b2    = (const float*)d_in[5];
    const float* rm_w1    = (const float*)d_in[6];
    const float* rm_b1    = (const float*)d_in[7];
    const float* rm_w2    = (const float*)d_in[8];
    const float* rm_b2    = (const float*)d_in[9];
    const float* mx_w1    = (const float*)d_in[10];
    const float* mx_b1    = (const float*)d_in[11];
    const float* mx_w2    = (const float*)d_in[12];
    const float* mx_b2    = (const float*)d_in[13];
    const float* my_w1    = (const float*)d_in[14];
    const float* my_b1    = (const float*)d_in[15];
    const float* my_w2    = (const float*)d_in[16];
    const float* my_b2    = (const float*)d_in[17];
    const float* ax_w1    = (const float*)d_in[18];
    const float* ax_b1    = (const float*)d_in[19];
    const float* ax_w2    = (const float*)d_in[20];
    const float* ax_b2    = (const float*)d_in[21];
    const float* ay_w1    = (const float*)d_in[22];
    const float* ay_b1    = (const float*)d_in[23];
    const float* ay_w2    = (const float*)d_in[24];
    const float* ay_b2    = (const float*)d_in[25];
    const float* mult_w   = (const float*)d_in[26];
    const float* addx_w   = (const float*)d_in[27];
    const float* addy_w   = (const float*)d_in[28];
    const float* gbias    = (const float*)d_in[29];
    (void)in_sizes; (void)n_in; (void)out_size; (void)ws_size;

    float* ws = (float*)d_ws;
    float* hid1p = ws;               // 6 x (64x512) = 196608 floats
    float* Pcat  = ws + 196608;      // 64x48x24     = 73728 floats
    float* shbuf = ws + 270336;      // 64x256       = 16384 floats
    float* rebuf = ws + 286720;      // 24x256       = 6144 floats

    // D0: L1 split-K6 -> hid1p[6]
    l1_kernel<<<dim3(32, 1, 6), 256, 0, stream>>>(in_h, st_w1, st_b1, hid1p);

    // D0b: shared layer 2 + prebias re[24][256] (176 blocks)
    l2re_kernel<<<176, 512, 0, stream>>>(hid1p, st_w2, st_b2,
                                         rank_emb, rm_w1, rm_b1, shbuf, rebuf);

    // D1: mega-middle -> Pcat (384 blocks, XCD-clustered by rank)
    mega_kernel<<<384, 512, 0, stream>>>(
        shbuf, rebuf,
        rm_w1, rm_w2, rm_b2,
        mx_w1, mx_b1, mx_w2, mx_b2,
        my_w1, my_b1, my_w2, my_b2,
        ax_w1, ax_b1, ax_w2, ax_b2,
        ay_w1, ay_b1, ay_w2, ay_b2,
        Pcat);

    // D2: fused spline + depth
    depth_fused_kernel<<<dim3(4, 4, 64), 256, 0, stream>>>(
        Pcat, mult_w, addx_w, addy_w, gbias, (float*)d_out);
}